// Round 3
// baseline (490.838 us; speedup 1.0000x reference)
//
#include <hip/hip_runtime.h>
#include <hip/hip_bf16.h>
#include <stdint.h>

#define B_ 4
#define T_ 2048
#define D_ 1024
#define M_ (B_*T_)
#define NH_ 16
#define HD_ 64

typedef __attribute__((ext_vector_type(8))) short bf16x8;
typedef __attribute__((ext_vector_type(4))) float f32x4;

__device__ __forceinline__ unsigned short f2bf(float f) {
  union { float f; unsigned u; } x; x.f = f;
  unsigned r = x.u + 0x7FFFu + ((x.u >> 16) & 1u);
  return (unsigned short)(r >> 16);
}

// ---------------- convert x (f32 -> bf16) ----------------
__global__ __launch_bounds__(256) void cvt_x_kernel(const float* __restrict__ x,
                                                    unsigned short* __restrict__ xb) {
  int i = (blockIdx.x * 256 + threadIdx.x) * 8;
  float4 a = *(const float4*)(x + i);
  float4 b = *(const float4*)(x + i + 4);
  ushort4 lo, hi;
  lo.x = f2bf(a.x); lo.y = f2bf(a.y); lo.z = f2bf(a.z); lo.w = f2bf(a.w);
  hi.x = f2bf(b.x); hi.y = f2bf(b.y); hi.z = f2bf(b.z); hi.w = f2bf(b.w);
  *(ushort4*)(xb + i) = lo;
  *(ushort4*)(xb + i + 4) = hi;
}

// ---------------- transpose W [K][N] f32 -> Wt [N][K] bf16 ----------------
__global__ __launch_bounds__(256) void transpose_w_kernel(const float* __restrict__ W,
                                                          unsigned short* __restrict__ Wt) {
  __shared__ unsigned short tile[64][72];
  const int bk = (blockIdx.x & 15) * 64;
  const int bn = (blockIdx.x >> 4) * 64;
  const int t = threadIdx.x;
  const int r0 = t >> 4;         // 0..15
  const int c0 = (t & 15) * 4;   // 0..60
#pragma unroll
  for (int p = 0; p < 4; ++p) {
    int r = p * 16 + r0;  // k within tile
    float4 v = *(const float4*)&W[(size_t)(bk + r) * D_ + bn + c0];
    tile[r][c0 + 0] = f2bf(v.x);
    tile[r][c0 + 1] = f2bf(v.y);
    tile[r][c0 + 2] = f2bf(v.z);
    tile[r][c0 + 3] = f2bf(v.w);
  }
  __syncthreads();
#pragma unroll
  for (int p = 0; p < 4; ++p) {
    int n = p * 16 + r0;  // n within tile
    ushort4 o;
    o.x = tile[c0 + 0][n];
    o.y = tile[c0 + 1][n];
    o.z = tile[c0 + 2][n];
    o.w = tile[c0 + 3][n];
    *(ushort4*)&Wt[(size_t)(bn + n) * D_ + bk + c0] = o;
  }
}

// ---------------- GEMM: C[M][1024] = A[M][1024] @ Bt[N][K]^T + bias ----------------
// OutT = unsigned short (bf16 bits) for internal tensors, float for d_out.
#define BM 128
#define BN 128
#define BK 64
template <typename OutT>
__global__ __launch_bounds__(256) void gemm_bf16_kernel(
    const unsigned short* __restrict__ A,   // [M][K] bf16
    const unsigned short* __restrict__ Bt,  // [N][K] bf16 (B transposed)
    const float* __restrict__ bias,         // [N] f32
    OutT* __restrict__ C)                   // [M][N]
{
  __shared__ unsigned short As[BM][BK + 8];
  __shared__ unsigned short Bs[BN][BK + 8];
  const int K = D_, N = D_;
  const int bm = blockIdx.y * BM;
  const int bn = blockIdx.x * BN;
  const int t = threadIdx.x;
  const int lane = t & 63;
  const int w = t >> 6;             // wave 0..3
  const int wr = (w >> 1) * 64;
  const int wc = (w & 1) * 64;
  const int lr = lane & 15;
  const int lk = (lane >> 4) * 8;
  const int cr = (lane >> 4) * 4;
  const int cc = lane & 15;

  f32x4 acc[4][4] = {};

  const int ar = t >> 3;        // 0..31 (row within pass)
  const int ac = (t & 7) * 8;   // col elem

  for (int k0 = 0; k0 < K; k0 += BK) {
#pragma unroll
    for (int p = 0; p < 4; ++p) {
      int row = p * 32 + ar;
      *(int4*)&As[row][ac] = *(const int4*)&A[(size_t)(bm + row) * K + k0 + ac];
      *(int4*)&Bs[row][ac] = *(const int4*)&Bt[(size_t)(bn + row) * K + k0 + ac];
    }
    __syncthreads();
#pragma unroll
    for (int kk = 0; kk < BK; kk += 32) {
      bf16x8 a[4], b[4];
#pragma unroll
      for (int m = 0; m < 4; ++m) a[m] = *(const bf16x8*)&As[wr + m * 16 + lr][kk + lk];
#pragma unroll
      for (int n = 0; n < 4; ++n) b[n] = *(const bf16x8*)&Bs[wc + n * 16 + lr][kk + lk];
#pragma unroll
      for (int m = 0; m < 4; ++m)
#pragma unroll
        for (int n = 0; n < 4; ++n)
          acc[m][n] = __builtin_amdgcn_mfma_f32_16x16x32_bf16(a[m], b[n], acc[m][n], 0, 0, 0);
    }
    __syncthreads();
  }

#pragma unroll
  for (int m = 0; m < 4; ++m)
#pragma unroll
    for (int n = 0; n < 4; ++n) {
      int col = bn + wc + n * 16 + cc;
      float bv = bias[col];
#pragma unroll
      for (int j = 0; j < 4; ++j) {
        int row = bm + wr + m * 16 + cr + j;
        float v = acc[m][n][j] + bv;
        if constexpr (__is_same(OutT, float)) {
          C[(size_t)row * N + col] = v;
        } else {
          C[(size_t)row * N + col] = f2bf(v);
        }
      }
    }
}

// ---------------- flash attention (causal, no scale) ----------------
// grid: (T/128, B*NH); 256 threads; wave w owns q rows [qtile+w*32, +32)
__global__ __launch_bounds__(256) void attn_kernel(
    const unsigned short* __restrict__ Qb,
    const unsigned short* __restrict__ Kb,
    const unsigned short* __restrict__ Vb,
    unsigned short* __restrict__ Ob)
{
  __shared__ unsigned short Ks[64][72];
  __shared__ unsigned short Vt[64][72];
  __shared__ unsigned short Ps[4][32][72];

  const int qt = blockIdx.x;
  const int bh = blockIdx.y;
  const int b = bh >> 4, h = bh & 15;
  const int qtile = qt * 128;
  const int t = threadIdx.x;
  const int lane = t & 63;
  const int w = t >> 6;
  const int lr = lane & 15;
  const int g = lane >> 4;
  const int lk = g * 8;
  const int cr = g * 4;
  const int cc = lane & 15;

  const size_t base = (size_t)(b * T_) * D_ + h * HD_;

  // Q fragments in registers (A-operand layout)
  bf16x8 qf[2][2];
#pragma unroll
  for (int m = 0; m < 2; ++m)
#pragma unroll
    for (int kk = 0; kk < 2; ++kk)
      qf[m][kk] = *(const bf16x8*)&Qb[base + (size_t)(qtile + w * 32 + m * 16 + lr) * D_ + kk * 32 + lk];

  f32x4 acc_o[2][4] = {};
  float mrun[2][4], lrun[2][4];
#pragma unroll
  for (int m = 0; m < 2; ++m)
#pragma unroll
    for (int j = 0; j < 4; ++j) { mrun[m][j] = -1e30f; lrun[m][j] = 0.f; }

  const int kvend = qtile + 128;
  for (int kvb = 0; kvb < kvend; kvb += 64) {
    __syncthreads();
    {
      int r = t >> 2;             // 0..63
      int c = (t & 3) * 16;       // 0,16,32,48
      const unsigned short* kg = &Kb[base + (size_t)(kvb + r) * D_ + c];
      *(int4*)&Ks[r][c] = *(const int4*)kg;
      *(int4*)&Ks[r][c + 8] = *(const int4*)(kg + 8);
      const unsigned short* vg = &Vb[base + (size_t)(kvb + r) * D_ + c];
      unsigned short tmp[16];
      *(int4*)&tmp[0] = *(const int4*)vg;
      *(int4*)&tmp[8] = *(const int4*)(vg + 8);
#pragma unroll
      for (int j = 0; j < 16; ++j) Vt[c + j][r] = tmp[j];
    }
    __syncthreads();

    // S = Q K^T  (32 x 64 per wave)
    f32x4 s[2][4] = {};
#pragma unroll
    for (int kk = 0; kk < 2; ++kk) {
      bf16x8 kf[4];
#pragma unroll
      for (int n = 0; n < 4; ++n) kf[n] = *(const bf16x8*)&Ks[n * 16 + lr][kk * 32 + lk];
#pragma unroll
      for (int m = 0; m < 2; ++m)
#pragma unroll
        for (int n = 0; n < 4; ++n)
          s[m][n] = __builtin_amdgcn_mfma_f32_16x16x32_bf16(qf[m][kk], kf[n], s[m][n], 0, 0, 0);
    }

    const bool diag = (kvb + 64 > qtile);
#pragma unroll
    for (int m = 0; m < 2; ++m) {
#pragma unroll
      for (int j = 0; j < 4; ++j) {
        const int qi = qtile + w * 32 + m * 16 + cr + j;
        if (diag) {
#pragma unroll
          for (int n = 0; n < 4; ++n) {
            int ki = kvb + n * 16 + cc;
            if (ki > qi) s[m][n][j] = -1e30f;
          }
        }
        float tmax = fmaxf(fmaxf(s[m][0][j], s[m][1][j]), fmaxf(s[m][2][j], s[m][3][j]));
#pragma unroll
        for (int d = 1; d < 16; d <<= 1) tmax = fmaxf(tmax, __shfl_xor(tmax, d));
        float mnew = fmaxf(mrun[m][j], tmax);
        float scale = __expf(mrun[m][j] - mnew);
        float psum = 0.f;
#pragma unroll
        for (int n = 0; n < 4; ++n) {
          float p = __expf(s[m][n][j] - mnew);
          s[m][n][j] = p;
          psum += p;
        }
#pragma unroll
        for (int d = 1; d < 16; d <<= 1) psum += __shfl_xor(psum, d);
        lrun[m][j] = lrun[m][j] * scale + psum;
        mrun[m][j] = mnew;
#pragma unroll
        for (int n = 0; n < 4; ++n) acc_o[m][n][j] *= scale;
#pragma unroll
        for (int n = 0; n < 4; ++n) Ps[w][m * 16 + cr + j][n * 16 + cc] = f2bf(s[m][n][j]);
      }
    }

    // O += P V
#pragma unroll
    for (int kk = 0; kk < 2; ++kk) {
      bf16x8 vf[4], pa[2];
#pragma unroll
      for (int m = 0; m < 2; ++m) pa[m] = *(const bf16x8*)&Ps[w][m * 16 + lr][kk * 32 + lk];
#pragma unroll
      for (int n = 0; n < 4; ++n) vf[n] = *(const bf16x8*)&Vt[n * 16 + lr][kk * 32 + lk];
#pragma unroll
      for (int m = 0; m < 2; ++m)
#pragma unroll
        for (int n = 0; n < 4; ++n)
          acc_o[m][n] = __builtin_amdgcn_mfma_f32_16x16x32_bf16(pa[m], vf[n], acc_o[m][n], 0, 0, 0);
    }
  }

#pragma unroll
  for (int m = 0; m < 2; ++m)
#pragma unroll
    for (int j = 0; j < 4; ++j) {
      float inv = 1.0f / lrun[m][j];
#pragma unroll
      for (int n = 0; n < 4; ++n)
        Ob[base + (size_t)(qtile + w * 32 + m * 16 + cr + j) * D_ + n * 16 + cc] =
            f2bf(acc_o[m][n][j] * inv);
    }
}

// ---------------- launch ----------------
extern "C" void kernel_launch(void* const* d_in, const int* in_sizes, int n_in,
                              void* d_out, int out_size, void* d_ws, size_t ws_size,
                              hipStream_t stream) {
  const float* x  = (const float*)d_in[0];
  const float* Wk = (const float*)d_in[1];
  const float* bk = (const float*)d_in[2];
  const float* Wq = (const float*)d_in[3];
  const float* bq = (const float*)d_in[4];
  const float* Wv = (const float*)d_in[5];
  const float* bv = (const float*)d_in[6];
  const float* Wp = (const float*)d_in[7];
  const float* bp = (const float*)d_in[8];

  char* ws = (char*)d_ws;
  // xb is dead after the V GEMM; attention output Ob aliases it. Total ws: 72 MB.
  unsigned short* xb  = (unsigned short*)(ws);
  unsigned short* Ob  = (unsigned short*)(ws);
  unsigned short* WqT = (unsigned short*)(ws + (16ull << 20));
  unsigned short* WkT = (unsigned short*)(ws + (18ull << 20));
  unsigned short* WvT = (unsigned short*)(ws + (20ull << 20));
  unsigned short* WpT = (unsigned short*)(ws + (22ull << 20));
  unsigned short* Qb  = (unsigned short*)(ws + (24ull << 20));
  unsigned short* Kb  = (unsigned short*)(ws + (40ull << 20));
  unsigned short* Vb  = (unsigned short*)(ws + (56ull << 20));

  hipLaunchKernelGGL(cvt_x_kernel, dim3((M_ * D_) / (256 * 8)), dim3(256), 0, stream, x, xb);
  hipLaunchKernelGGL(transpose_w_kernel, dim3(256), dim3(256), 0, stream, Wq, WqT);
  hipLaunchKernelGGL(transpose_w_kernel, dim3(256), dim3(256), 0, stream, Wk, WkT);
  hipLaunchKernelGGL(transpose_w_kernel, dim3(256), dim3(256), 0, stream, Wv, WvT);
  hipLaunchKernelGGL(transpose_w_kernel, dim3(256), dim3(256), 0, stream, Wp, WpT);

  dim3 ggrid(D_ / BN, M_ / BM);
  hipLaunchKernelGGL((gemm_bf16_kernel<unsigned short>), ggrid, dim3(256), 0, stream, xb, WqT, bq, Qb);
  hipLaunchKernelGGL((gemm_bf16_kernel<unsigned short>), ggrid, dim3(256), 0, stream, xb, WkT, bk, Kb);
  hipLaunchKernelGGL((gemm_bf16_kernel<unsigned short>), ggrid, dim3(256), 0, stream, xb, WvT, bv, Vb);

  hipLaunchKernelGGL(attn_kernel, dim3(T_ / 128, B_ * NH_), dim3(256), 0, stream, Qb, Kb, Vb, Ob);

  hipLaunchKernelGGL((gemm_bf16_kernel<float>), ggrid, dim3(256), 0, stream, Ob, WpT, bp,
                     (float*)d_out);
}

// Round 4
// 387.277 us; speedup vs baseline: 1.2674x; 1.2674x over previous
//
#include <hip/hip_runtime.h>
#include <hip/hip_bf16.h>
#include <stdint.h>

#define B_ 4
#define T_ 2048
#define D_ 1024
#define M_ (B_*T_)
#define NH_ 16
#define HD_ 64

typedef __attribute__((ext_vector_type(8))) short bf16x8;
typedef __attribute__((ext_vector_type(4))) float f32x4;

// async global->LDS, 16B per lane; LDS dest = wave-uniform base + lane*16
#define GLOAD_LDS16(gp, lp)                                                   \
  __builtin_amdgcn_global_load_lds(                                           \
      (const __attribute__((address_space(1))) void*)(gp),                    \
      (__attribute__((address_space(3))) void*)(lp), 16, 0, 0)

__device__ __forceinline__ unsigned short f2bf(float f) {
  union { float f; unsigned u; } x; x.f = f;
  unsigned r = x.u + 0x7FFFu + ((x.u >> 16) & 1u);
  return (unsigned short)(r >> 16);
}

// ---------------- convert x (f32 -> bf16) ----------------
__global__ __launch_bounds__(256) void cvt_x_kernel(const float* __restrict__ x,
                                                    unsigned short* __restrict__ xb) {
  int i = (blockIdx.x * 256 + threadIdx.x) * 8;
  float4 a = *(const float4*)(x + i);
  float4 b = *(const float4*)(x + i + 4);
  ushort4 lo, hi;
  lo.x = f2bf(a.x); lo.y = f2bf(a.y); lo.z = f2bf(a.z); lo.w = f2bf(a.w);
  hi.x = f2bf(b.x); hi.y = f2bf(b.y); hi.z = f2bf(b.z); hi.w = f2bf(b.w);
  *(ushort4*)(xb + i) = lo;
  *(ushort4*)(xb + i + 4) = hi;
}

// ---------------- transpose W [K][N] f32 -> Wt [N][K] bf16 ----------------
__global__ __launch_bounds__(256) void transpose_w_kernel(const float* __restrict__ W,
                                                          unsigned short* __restrict__ Wt) {
  __shared__ unsigned short tile[64][72];
  const int bk = (blockIdx.x & 15) * 64;
  const int bn = (blockIdx.x >> 4) * 64;
  const int t = threadIdx.x;
  const int r0 = t >> 4;         // 0..15
  const int c0 = (t & 15) * 4;   // 0..60
#pragma unroll
  for (int p = 0; p < 4; ++p) {
    int r = p * 16 + r0;  // k within tile
    float4 v = *(const float4*)&W[(size_t)(bk + r) * D_ + bn + c0];
    tile[r][c0 + 0] = f2bf(v.x);
    tile[r][c0 + 1] = f2bf(v.y);
    tile[r][c0 + 2] = f2bf(v.z);
    tile[r][c0 + 3] = f2bf(v.w);
  }
  __syncthreads();
#pragma unroll
  for (int p = 0; p < 4; ++p) {
    int n = p * 16 + r0;  // n within tile
    ushort4 o;
    o.x = tile[c0 + 0][n];
    o.y = tile[c0 + 1][n];
    o.z = tile[c0 + 2][n];
    o.w = tile[c0 + 3][n];
    *(ushort4*)&Wt[(size_t)(bn + n) * D_ + bk + c0] = o;
  }
}

// ---------------- GEMM (m97 structure): linear LDS + global_load_lds ----------------
#define BM 128
#define BN 128
#define BK 64
template <typename OutT>
__global__ __launch_bounds__(256) void gemm_bf16_kernel(
    const unsigned short* __restrict__ A,   // [M][K] bf16
    const unsigned short* __restrict__ Bt,  // [N][K] bf16 (B transposed)
    const float* __restrict__ bias,         // [N] f32
    OutT* __restrict__ C)                   // [M][N]
{
  __shared__ unsigned short As[BM * BK];   // linear [row][64] -- NO padding (global_load_lds)
  __shared__ unsigned short Bs[BN * BK];
  const int K = D_, N = D_;
  const int bm = blockIdx.y * BM;
  const int bn = blockIdx.x * BN;
  const int t = threadIdx.x;
  const int lane = t & 63;
  const int w = t >> 6;             // wave 0..3
  const int wr = (w >> 1) * 64;
  const int wc = (w & 1) * 64;
  const int lr = lane & 15;
  const int lk = (lane >> 4) * 8;
  const int cr = (lane >> 4) * 4;
  const int cc = lane & 15;

  // staging: per wave-instr, 64 lanes x 16B = 1KB = 8 rows of 64 shorts
  const int srow = lane >> 3;        // 0..7
  const int scol = (lane & 7) * 8;   // 0..56

  f32x4 acc[4][4] = {};

  for (int k0 = 0; k0 < K; k0 += BK) {
#pragma unroll
    for (int i = 0; i < 4; ++i) {
      const int rbase = w * 32 + i * 8;              // rows this instr covers
      GLOAD_LDS16(&A[(size_t)(bm + rbase + srow) * K + k0 + scol], &As[rbase * BK]);
      GLOAD_LDS16(&Bt[(size_t)(bn + rbase + srow) * K + k0 + scol], &Bs[rbase * BK]);
    }
    __syncthreads();   // drains vmcnt (incl. global_load_lds)
#pragma unroll
    for (int kk = 0; kk < BK; kk += 32) {
      bf16x8 a[4], b[4];
#pragma unroll
      for (int m = 0; m < 4; ++m) a[m] = *(const bf16x8*)&As[(wr + m * 16 + lr) * BK + kk + lk];
#pragma unroll
      for (int n = 0; n < 4; ++n) b[n] = *(const bf16x8*)&Bs[(wc + n * 16 + lr) * BK + kk + lk];
#pragma unroll
      for (int m = 0; m < 4; ++m)
#pragma unroll
        for (int n = 0; n < 4; ++n)
          acc[m][n] = __builtin_amdgcn_mfma_f32_16x16x32_bf16(a[m], b[n], acc[m][n], 0, 0, 0);
    }
    __syncthreads();
  }

#pragma unroll
  for (int m = 0; m < 4; ++m)
#pragma unroll
    for (int n = 0; n < 4; ++n) {
      int col = bn + wc + n * 16 + cc;
      float bv = bias[col];
#pragma unroll
      for (int j = 0; j < 4; ++j) {
        int row = bm + wr + m * 16 + cr + j;
        float v = acc[m][n][j] + bv;
        if constexpr (__is_same(OutT, float)) {
          C[(size_t)row * N + col] = v;
        } else {
          C[(size_t)row * N + col] = f2bf(v);
        }
      }
    }
}

// ---------------- flash attention (causal, no scale), balanced q-tile pairs --------
// grid: (8, B*NH); block pid handles q-tiles {pid, 15-pid} -> 17 kv-iters each.
__global__ __launch_bounds__(256) void attn_kernel(
    const unsigned short* __restrict__ Qb,
    const unsigned short* __restrict__ Kb,
    const unsigned short* __restrict__ Vb,
    unsigned short* __restrict__ Ob)
{
  __shared__ unsigned short Ks[64][72];
  __shared__ unsigned short Vt[64][72];
  __shared__ unsigned short Ps[4][32][72];

  const int pid = blockIdx.x;          // 0..7
  const int bh = blockIdx.y;
  const int b = bh >> 4, h = bh & 15;
  const int t = threadIdx.x;
  const int lane = t & 63;
  const int w = t >> 6;
  const int lr = lane & 15;
  const int g = lane >> 4;
  const int lk = g * 8;
  const int cr = g * 4;
  const int cc = lane & 15;

  const size_t base = (size_t)(b * T_) * D_ + h * HD_;

  for (int hp = 0; hp < 2; ++hp) {
    const int qtile = (hp == 0 ? pid : 15 - pid) * 128;

    // Q fragments in registers (A-operand layout)
    bf16x8 qf[2][2];
#pragma unroll
    for (int m = 0; m < 2; ++m)
#pragma unroll
      for (int kk = 0; kk < 2; ++kk)
        qf[m][kk] = *(const bf16x8*)&Qb[base + (size_t)(qtile + w * 32 + m * 16 + lr) * D_ + kk * 32 + lk];

    f32x4 acc_o[2][4] = {};
    float mrun[2][4], lrun[2][4];
#pragma unroll
    for (int m = 0; m < 2; ++m)
#pragma unroll
      for (int j = 0; j < 4; ++j) { mrun[m][j] = -1e30f; lrun[m][j] = 0.f; }

    const int kvend = qtile + 128;
    for (int kvb = 0; kvb < kvend; kvb += 64) {
      __syncthreads();
      {
        int r = t >> 2;             // 0..63
        int c = (t & 3) * 16;       // 0,16,32,48
        const unsigned short* kg = &Kb[base + (size_t)(kvb + r) * D_ + c];
        *(int4*)&Ks[r][c] = *(const int4*)kg;
        *(int4*)&Ks[r][c + 8] = *(const int4*)(kg + 8);
        const unsigned short* vg = &Vb[base + (size_t)(kvb + r) * D_ + c];
        unsigned short tmp[16];
        *(int4*)&tmp[0] = *(const int4*)vg;
        *(int4*)&tmp[8] = *(const int4*)(vg + 8);
#pragma unroll
        for (int j = 0; j < 16; ++j) Vt[c + j][r] = tmp[j];
      }
      __syncthreads();

      // S = Q K^T  (32 x 64 per wave)
      f32x4 s[2][4] = {};
#pragma unroll
      for (int kk = 0; kk < 2; ++kk) {
        bf16x8 kf[4];
#pragma unroll
        for (int n = 0; n < 4; ++n) kf[n] = *(const bf16x8*)&Ks[n * 16 + lr][kk * 32 + lk];
#pragma unroll
        for (int m = 0; m < 2; ++m)
#pragma unroll
          for (int n = 0; n < 4; ++n)
            s[m][n] = __builtin_amdgcn_mfma_f32_16x16x32_bf16(qf[m][kk], kf[n], s[m][n], 0, 0, 0);
      }

      const bool diag = (kvb + 64 > qtile);
#pragma unroll
      for (int m = 0; m < 2; ++m) {
#pragma unroll
        for (int j = 0; j < 4; ++j) {
          const int qi = qtile + w * 32 + m * 16 + cr + j;
          if (diag) {
#pragma unroll
            for (int n = 0; n < 4; ++n) {
              int ki = kvb + n * 16 + cc;
              if (ki > qi) s[m][n][j] = -1e30f;
            }
          }
          float tmax = fmaxf(fmaxf(s[m][0][j], s[m][1][j]), fmaxf(s[m][2][j], s[m][3][j]));
#pragma unroll
          for (int d = 1; d < 16; d <<= 1) tmax = fmaxf(tmax, __shfl_xor(tmax, d));
          float mnew = fmaxf(mrun[m][j], tmax);
          float scale = __expf(mrun[m][j] - mnew);
          float psum = 0.f;
#pragma unroll
          for (int n = 0; n < 4; ++n) {
            float p = __expf(s[m][n][j] - mnew);
            s[m][n][j] = p;
            psum += p;
          }
#pragma unroll
          for (int d = 1; d < 16; d <<= 1) psum += __shfl_xor(psum, d);
          lrun[m][j] = lrun[m][j] * scale + psum;
          mrun[m][j] = mnew;
#pragma unroll
          for (int n = 0; n < 4; ++n) acc_o[m][n][j] *= scale;
#pragma unroll
          for (int n = 0; n < 4; ++n) Ps[w][m * 16 + cr + j][n * 16 + cc] = f2bf(s[m][n][j]);
        }
      }

      // O += P V
#pragma unroll
      for (int kk = 0; kk < 2; ++kk) {
        bf16x8 vf[4], pa[2];
#pragma unroll
        for (int m = 0; m < 2; ++m) pa[m] = *(const bf16x8*)&Ps[w][m * 16 + lr][kk * 32 + lk];
#pragma unroll
        for (int n = 0; n < 4; ++n) vf[n] = *(const bf16x8*)&Vt[n * 16 + lr][kk * 32 + lk];
#pragma unroll
        for (int m = 0; m < 2; ++m)
#pragma unroll
          for (int n = 0; n < 4; ++n)
            acc_o[m][n] = __builtin_amdgcn_mfma_f32_16x16x32_bf16(pa[m], vf[n], acc_o[m][n], 0, 0, 0);
      }
    }

#pragma unroll
    for (int m = 0; m < 2; ++m)
#pragma unroll
      for (int j = 0; j < 4; ++j) {
        float inv = 1.0f / lrun[m][j];
#pragma unroll
        for (int n = 0; n < 4; ++n)
          Ob[base + (size_t)(qtile + w * 32 + m * 16 + cr + j) * D_ + n * 16 + cc] =
              f2bf(acc_o[m][n][j] * inv);
      }
  }
}

// ---------------- launch ----------------
extern "C" void kernel_launch(void* const* d_in, const int* in_sizes, int n_in,
                              void* d_out, int out_size, void* d_ws, size_t ws_size,
                              hipStream_t stream) {
  const float* x  = (const float*)d_in[0];
  const float* Wk = (const float*)d_in[1];
  const float* bk = (const float*)d_in[2];
  const float* Wq = (const float*)d_in[3];
  const float* bq = (const float*)d_in[4];
  const float* Wv = (const float*)d_in[5];
  const float* bv = (const float*)d_in[6];
  const float* Wp = (const float*)d_in[7];
  const float* bp = (const float*)d_in[8];

  char* ws = (char*)d_ws;
  // xb is dead after the V GEMM; attention output Ob aliases it. Total ws: 72 MB.
  unsigned short* xb  = (unsigned short*)(ws);
  unsigned short* Ob  = (unsigned short*)(ws);
  unsigned short* WqT = (unsigned short*)(ws + (16ull << 20));
  unsigned short* WkT = (unsigned short*)(ws + (18ull << 20));
  unsigned short* WvT = (unsigned short*)(ws + (20ull << 20));
  unsigned short* WpT = (unsigned short*)(ws + (22ull << 20));
  unsigned short* Qb  = (unsigned short*)(ws + (24ull << 20));
  unsigned short* Kb  = (unsigned short*)(ws + (40ull << 20));
  unsigned short* Vb  = (unsigned short*)(ws + (56ull << 20));

  hipLaunchKernelGGL(cvt_x_kernel, dim3((M_ * D_) / (256 * 8)), dim3(256), 0, stream, x, xb);
  hipLaunchKernelGGL(transpose_w_kernel, dim3(256), dim3(256), 0, stream, Wq, WqT);
  hipLaunchKernelGGL(transpose_w_kernel, dim3(256), dim3(256), 0, stream, Wk, WkT);
  hipLaunchKernelGGL(transpose_w_kernel, dim3(256), dim3(256), 0, stream, Wv, WvT);
  hipLaunchKernelGGL(transpose_w_kernel, dim3(256), dim3(256), 0, stream, Wp, WpT);

  dim3 ggrid(D_ / BN, M_ / BM);
  hipLaunchKernelGGL((gemm_bf16_kernel<unsigned short>), ggrid, dim3(256), 0, stream, xb, WqT, bq, Qb);
  hipLaunchKernelGGL((gemm_bf16_kernel<unsigned short>), ggrid, dim3(256), 0, stream, xb, WkT, bk, Kb);
  hipLaunchKernelGGL((gemm_bf16_kernel<unsigned short>), ggrid, dim3(256), 0, stream, xb, WvT, bv, Vb);

  hipLaunchKernelGGL(attn_kernel, dim3(8, B_ * NH_), dim3(256), 0, stream, Qb, Kb, Vb, Ob);

  hipLaunchKernelGGL((gemm_bf16_kernel<float>), ggrid, dim3(256), 0, stream, Ob, WpT, bp,
                     (float*)d_out);
}

// Round 5
// 318.634 us; speedup vs baseline: 1.5404x; 1.2154x over previous
//
#include <hip/hip_runtime.h>
#include <hip/hip_bf16.h>
#include <stdint.h>

#define B_ 4
#define T_ 2048
#define D_ 1024
#define M_ (B_*T_)
#define NH_ 16
#define HD_ 64

typedef __attribute__((ext_vector_type(8))) short bf16x8;
typedef __attribute__((ext_vector_type(4))) float f32x4;

// async global->LDS, 16B per lane; LDS dest = wave-uniform base + lane*16
#define GLOAD_LDS16(gp, lp)                                                   \
  __builtin_amdgcn_global_load_lds(                                           \
      (const __attribute__((address_space(1))) void*)(gp),                    \
      (__attribute__((address_space(3))) void*)(lp), 16, 0, 0)

__device__ __forceinline__ unsigned short f2bf(float f) {
  union { float f; unsigned u; } x; x.f = f;
  unsigned r = x.u + 0x7FFFu + ((x.u >> 16) & 1u);
  return (unsigned short)(r >> 16);
}

// ---------------- convert x (f32 -> bf16) ----------------
__global__ __launch_bounds__(256) void cvt_x_kernel(const float* __restrict__ x,
                                                    unsigned short* __restrict__ xb) {
  int i = (blockIdx.x * 256 + threadIdx.x) * 8;
  float4 a = *(const float4*)(x + i);
  float4 b = *(const float4*)(x + i + 4);
  ushort4 lo, hi;
  lo.x = f2bf(a.x); lo.y = f2bf(a.y); lo.z = f2bf(a.z); lo.w = f2bf(a.w);
  hi.x = f2bf(b.x); hi.y = f2bf(b.y); hi.z = f2bf(b.z); hi.w = f2bf(b.w);
  *(ushort4*)(xb + i) = lo;
  *(ushort4*)(xb + i + 4) = hi;
}

// ---------------- transpose all 4 W [K][N] f32 -> Wt [N][K] bf16 (grid.y selects) ----
__global__ __launch_bounds__(256) void transpose_w4_kernel(
    const float* __restrict__ W0, const float* __restrict__ W1,
    const float* __restrict__ W2, const float* __restrict__ W3,
    unsigned short* __restrict__ O0, unsigned short* __restrict__ O1,
    unsigned short* __restrict__ O2, unsigned short* __restrict__ O3) {
  const float* W = (blockIdx.y == 0) ? W0 : (blockIdx.y == 1) ? W1 : (blockIdx.y == 2) ? W2 : W3;
  unsigned short* Wt = (blockIdx.y == 0) ? O0 : (blockIdx.y == 1) ? O1 : (blockIdx.y == 2) ? O2 : O3;
  __shared__ unsigned short tile[64][72];
  const int bk = (blockIdx.x & 15) * 64;
  const int bn = (blockIdx.x >> 4) * 64;
  const int t = threadIdx.x;
  const int r0 = t >> 4;         // 0..15
  const int c0 = (t & 15) * 4;   // 0..60
#pragma unroll
  for (int p = 0; p < 4; ++p) {
    int r = p * 16 + r0;
    float4 v = *(const float4*)&W[(size_t)(bk + r) * D_ + bn + c0];
    tile[r][c0 + 0] = f2bf(v.x);
    tile[r][c0 + 1] = f2bf(v.y);
    tile[r][c0 + 2] = f2bf(v.z);
    tile[r][c0 + 3] = f2bf(v.w);
  }
  __syncthreads();
#pragma unroll
  for (int p = 0; p < 4; ++p) {
    int n = p * 16 + r0;
    ushort4 o;
    o.x = tile[c0 + 0][n];
    o.y = tile[c0 + 1][n];
    o.z = tile[c0 + 2][n];
    o.w = tile[c0 + 3][n];
    *(ushort4*)&Wt[(size_t)(bn + n) * D_ + bk + c0] = o;
  }
}

// ---------------- transpose V (bf16) per batch: Vtg[b][c][t] = Vb[b][t][c] ----------
// grid: (16, 32, 4)  -> (c-tile, t-tile, b)
__global__ __launch_bounds__(256) void transpose_v_kernel(
    const unsigned short* __restrict__ Vb, unsigned short* __restrict__ Vtg) {
  __shared__ unsigned short tile[64][72];
  const int ct = blockIdx.x * 64;
  const int tt = blockIdx.y * 64;
  const size_t bofs_in  = (size_t)blockIdx.z * T_ * D_;
  const size_t bofs_out = (size_t)blockIdx.z * D_ * T_;
  const int t = threadIdx.x;
  const int r0 = t >> 4;
  const int c0 = (t & 15) * 4;
#pragma unroll
  for (int p = 0; p < 4; ++p) {
    int r = p * 16 + r0;   // t-within
    *(ushort4*)&tile[r][c0] = *(const ushort4*)&Vb[bofs_in + (size_t)(tt + r) * D_ + ct + c0];
  }
  __syncthreads();
#pragma unroll
  for (int p = 0; p < 4; ++p) {
    int n = p * 16 + r0;   // c-within (output row)
    ushort4 o;
    o.x = tile[c0 + 0][n];
    o.y = tile[c0 + 1][n];
    o.z = tile[c0 + 2][n];
    o.w = tile[c0 + 3][n];
    *(ushort4*)&Vtg[bofs_out + (size_t)(ct + n) * T_ + tt + c0] = o;
  }
}

// ---------------- GEMM core (m97 structure): linear LDS + global_load_lds ----------
#define BM 128
#define BN 128
#define BK 64
template <typename OutT>
__device__ __forceinline__ void gemm_core(
    const unsigned short* __restrict__ A, const unsigned short* __restrict__ Bt,
    const float* __restrict__ bias, OutT* __restrict__ C,
    unsigned short* As, unsigned short* Bs, int bm, int bn) {
  const int K = D_, N = D_;
  const int t = threadIdx.x;
  const int lane = t & 63;
  const int w = t >> 6;
  const int wr = (w >> 1) * 64;
  const int wc = (w & 1) * 64;
  const int lr = lane & 15;
  const int lk = (lane >> 4) * 8;
  const int cr = (lane >> 4) * 4;
  const int cc = lane & 15;
  const int srow = lane >> 3;
  const int scol = (lane & 7) * 8;

  f32x4 acc[4][4] = {};

  for (int k0 = 0; k0 < K; k0 += BK) {
#pragma unroll
    for (int i = 0; i < 4; ++i) {
      const int rbase = w * 32 + i * 8;
      GLOAD_LDS16(&A[(size_t)(bm + rbase + srow) * K + k0 + scol], &As[rbase * BK]);
      GLOAD_LDS16(&Bt[(size_t)(bn + rbase + srow) * K + k0 + scol], &Bs[rbase * BK]);
    }
    __syncthreads();
#pragma unroll
    for (int kk = 0; kk < BK; kk += 32) {
      bf16x8 a[4], b[4];
#pragma unroll
      for (int m = 0; m < 4; ++m) a[m] = *(const bf16x8*)&As[(wr + m * 16 + lr) * BK + kk + lk];
#pragma unroll
      for (int n = 0; n < 4; ++n) b[n] = *(const bf16x8*)&Bs[(wc + n * 16 + lr) * BK + kk + lk];
#pragma unroll
      for (int m = 0; m < 4; ++m)
#pragma unroll
        for (int n = 0; n < 4; ++n)
          acc[m][n] = __builtin_amdgcn_mfma_f32_16x16x32_bf16(a[m], b[n], acc[m][n], 0, 0, 0);
    }
    __syncthreads();
  }

#pragma unroll
  for (int m = 0; m < 4; ++m)
#pragma unroll
    for (int n = 0; n < 4; ++n) {
      int col = bn + wc + n * 16 + cc;
      float bv = bias[col];
#pragma unroll
      for (int j = 0; j < 4; ++j) {
        int row = bm + wr + m * 16 + cr + j;
        float v = acc[m][n][j] + bv;
        if constexpr (__is_same(OutT, float)) {
          C[(size_t)row * N + col] = v;
        } else {
          C[(size_t)row * N + col] = f2bf(v);
        }
      }
    }
}

// fused QKV: grid (8, 64, 3); z selects weight/bias/output
__global__ __launch_bounds__(256) void gemm_qkv_kernel(
    const unsigned short* __restrict__ xb,
    const unsigned short* __restrict__ WqT, const unsigned short* __restrict__ WkT,
    const unsigned short* __restrict__ WvT,
    const float* __restrict__ bq, const float* __restrict__ bk, const float* __restrict__ bv,
    unsigned short* __restrict__ Qb, unsigned short* __restrict__ Kb,
    unsigned short* __restrict__ Vb) {
  __shared__ unsigned short As[BM * BK];
  __shared__ unsigned short Bs[BN * BK];
  const int z = blockIdx.z;
  const unsigned short* Bt = (z == 0) ? WqT : (z == 1) ? WkT : WvT;
  const float* bias = (z == 0) ? bq : (z == 1) ? bk : bv;
  unsigned short* C = (z == 0) ? Qb : (z == 1) ? Kb : Vb;
  gemm_core<unsigned short>(xb, Bt, bias, C, As, Bs, blockIdx.y * BM, blockIdx.x * BN);
}

__global__ __launch_bounds__(256) void gemm_proj_kernel(
    const unsigned short* __restrict__ A, const unsigned short* __restrict__ Bt,
    const float* __restrict__ bias, float* __restrict__ C) {
  __shared__ unsigned short As[BM * BK];
  __shared__ unsigned short Bs[BN * BK];
  gemm_core<float>(A, Bt, bias, C, As, Bs, blockIdx.y * BM, blockIdx.x * BN);
}

// ---------------- flash attention (causal), swapped QK^T, balanced q-tile pairs -----
// grid: (8, B*NH); block pid handles q-tiles {pid, 15-pid} -> 17 kv-iters each.
__global__ __launch_bounds__(256) void attn_kernel(
    const unsigned short* __restrict__ Qb,
    const unsigned short* __restrict__ Kb,
    const unsigned short* __restrict__ Vtg,   // [B][D][T] per-batch transposed V
    unsigned short* __restrict__ Ob)
{
  __shared__ unsigned short Ks[64][72];
  __shared__ unsigned short Vt[64][72];
  __shared__ unsigned int   Ps32[4][32][36];   // bf16 pairs, row stride 72 shorts

  const int pid = blockIdx.x;
  const int bh = blockIdx.y;
  const int b = bh >> 4, h = bh & 15;
  const int t = threadIdx.x;
  const int lane = t & 63;
  const int w = t >> 6;
  const int lr = lane & 15;        // q-col of S^T; also frag row
  const int g = lane >> 4;
  const int lk = g * 8;
  const int cr = g * 4;
  const int cc = lane & 15;

  const size_t base   = (size_t)(b * T_) * D_ + h * HD_;        // Q/K/O rows
  const size_t vbase  = ((size_t)b * D_ + h * HD_) * T_;        // Vtg rows (d-major)

  for (int hp = 0; hp < 2; ++hp) {
    const int qtile = (hp == 0 ? pid : 15 - pid) * 128;

    // Q fragments (B-operand; load pattern identical to A-frag)
    bf16x8 qf[2][2];
#pragma unroll
    for (int m = 0; m < 2; ++m)
#pragma unroll
      for (int kk = 0; kk < 2; ++kk)
        qf[m][kk] = *(const bf16x8*)&Qb[base + (size_t)(qtile + w * 32 + m * 16 + lr) * D_ + kk * 32 + lk];

    f32x4 acc_o[2][4] = {};
    float mrun[2], lrun[2];
#pragma unroll
    for (int m = 0; m < 2; ++m) { mrun[m] = -1e30f; lrun[m] = 0.f; }

    const int kvend = qtile + 128;
    for (int kvb = 0; kvb < kvend; kvb += 64) {
      __syncthreads();
      {
        int r = t >> 2;             // 0..63
        int c = (t & 3) * 16;       // 0,16,32,48
        const unsigned short* kg = &Kb[base + (size_t)(kvb + r) * D_ + c];
        *(int4*)&Ks[r][c]     = *(const int4*)kg;
        *(int4*)&Ks[r][c + 8] = *(const int4*)(kg + 8);
        const unsigned short* vg = &Vtg[vbase + (size_t)r * T_ + kvb + c];
        *(int4*)&Vt[r][c]     = *(const int4*)vg;
        *(int4*)&Vt[r][c + 8] = *(const int4*)(vg + 8);
      }
      __syncthreads();

      // S^T = K Q^T : s[m][n] = mfma(A=kf[n], B=qf[m]); lane: q = lane&15, k = n*16+g*4+j
      f32x4 s[2][4] = {};
#pragma unroll
      for (int kk = 0; kk < 2; ++kk) {
        bf16x8 kf[4];
#pragma unroll
        for (int n = 0; n < 4; ++n) kf[n] = *(const bf16x8*)&Ks[n * 16 + lr][kk * 32 + lk];
#pragma unroll
        for (int m = 0; m < 2; ++m)
#pragma unroll
          for (int n = 0; n < 4; ++n)
            s[m][n] = __builtin_amdgcn_mfma_f32_16x16x32_bf16(kf[n], qf[m][kk], s[m][n], 0, 0, 0);
      }

      const bool diag = (kvb + 64 > qtile);
      bool mact[2];
#pragma unroll
      for (int m = 0; m < 2; ++m) {
        // fully-masked subtile? (wave-uniform): max q-row < kvb
        mact[m] = (qtile + w * 32 + m * 16 + 15 >= kvb);
        if (!mact[m]) continue;

        const int qi = qtile + w * 32 + m * 16 + lr;   // this lane's q-row
        if (diag) {
#pragma unroll
          for (int n = 0; n < 4; ++n)
#pragma unroll
            for (int j = 0; j < 4; ++j) {
              int ki = kvb + n * 16 + cr + j;
              if (ki > qi) s[m][n][j] = -1e30f;
            }
        }
        // row max: 16 in-lane + cross-g (xor 16, 32)
        float tmax = -1e30f;
#pragma unroll
        for (int n = 0; n < 4; ++n)
          tmax = fmaxf(tmax, fmaxf(fmaxf(s[m][n][0], s[m][n][1]), fmaxf(s[m][n][2], s[m][n][3])));
        tmax = fmaxf(tmax, __shfl_xor(tmax, 16));
        tmax = fmaxf(tmax, __shfl_xor(tmax, 32));
        float mnew = fmaxf(mrun[m], tmax);
        float sc = __expf(mrun[m] - mnew);
        float psum = 0.f;
#pragma unroll
        for (int n = 0; n < 4; ++n)
#pragma unroll
          for (int j = 0; j < 4; ++j) {
            float p = __expf(s[m][n][j] - mnew);
            s[m][n][j] = p;
            psum += p;
          }
        psum += __shfl_xor(psum, 16);
        psum += __shfl_xor(psum, 32);
        lrun[m] = lrun[m] * sc + psum;
        mrun[m] = mnew;

        // pack P pairs (k=2h, 2h+1) -> u32, conflict-free writes
#pragma unroll
        for (int n = 0; n < 4; ++n)
#pragma unroll
          for (int hh = 0; hh < 2; ++hh) {
            float lo = s[m][n][2 * hh], hi = s[m][n][2 * hh + 1];
            unsigned pk;
            asm("v_cvt_pk_bf16_f32 %0, %1, %2" : "=v"(pk) : "v"(lo), "v"(hi));
            Ps32[w][m * 16 + lr][n * 8 + g * 2 + hh] = pk;
          }

        // rescale acc_o rows (row = g*4+j); broadcast sc from lane (g*16 + row)
#pragma unroll
        for (int j = 0; j < 4; ++j) {
          float scj = __shfl(sc, (lane & 48) | (cr + j));
#pragma unroll
          for (int n = 0; n < 4; ++n) acc_o[m][n][j] *= scj;
        }
      }

      // O += P V : pa = A-frag of P (rows q), vf = B-frag from Vt rows (d-major)
#pragma unroll
      for (int kk = 0; kk < 2; ++kk) {
        bf16x8 vf[4];
#pragma unroll
        for (int n = 0; n < 4; ++n) vf[n] = *(const bf16x8*)&Vt[n * 16 + lr][kk * 32 + lk];
#pragma unroll
        for (int m = 0; m < 2; ++m) {
          if (!mact[m]) continue;
          bf16x8 pa = *(const bf16x8*)((const unsigned short*)&Ps32[w][m * 16 + lr][0] + kk * 32 + lk);
#pragma unroll
          for (int n = 0; n < 4; ++n)
            acc_o[m][n] = __builtin_amdgcn_mfma_f32_16x16x32_bf16(pa, vf[n], acc_o[m][n], 0, 0, 0);
        }
      }
    }

    // epilogue: inv l for row g*4+j via shfl from lane (g*16 + row)
#pragma unroll
    for (int m = 0; m < 2; ++m)
#pragma unroll
      for (int j = 0; j < 4; ++j) {
        float inv = 1.0f / __shfl(lrun[m], (lane & 48) | (cr + j));
#pragma unroll
        for (int n = 0; n < 4; ++n)
          Ob[base + (size_t)(qtile + w * 32 + m * 16 + cr + j) * D_ + n * 16 + cc] =
              f2bf(acc_o[m][n][j] * inv);
      }
  }
}

// ---------------- launch ----------------
extern "C" void kernel_launch(void* const* d_in, const int* in_sizes, int n_in,
                              void* d_out, int out_size, void* d_ws, size_t ws_size,
                              hipStream_t stream) {
  const float* x  = (const float*)d_in[0];
  const float* Wk = (const float*)d_in[1];
  const float* bk = (const float*)d_in[2];
  const float* Wq = (const float*)d_in[3];
  const float* bq = (const float*)d_in[4];
  const float* Wv = (const float*)d_in[5];
  const float* bv = (const float*)d_in[6];
  const float* Wp = (const float*)d_in[7];
  const float* bp = (const float*)d_in[8];

  char* ws = (char*)d_ws;
  unsigned short* xb  = (unsigned short*)(ws);            // 16MB; Ob aliases after use
  unsigned short* Ob  = (unsigned short*)(ws);
  unsigned short* WqT = (unsigned short*)(ws + (16ull << 20));
  unsigned short* WkT = (unsigned short*)(ws + (18ull << 20));
  unsigned short* WvT = (unsigned short*)(ws + (20ull << 20));
  unsigned short* WpT = (unsigned short*)(ws + (22ull << 20));
  unsigned short* Qb  = (unsigned short*)(ws + (24ull << 20));
  unsigned short* Kb  = (unsigned short*)(ws + (40ull << 20));
  unsigned short* Vb  = (unsigned short*)(ws + (56ull << 20));
  unsigned short* Vtg = (unsigned short*)(ws + (72ull << 20));  // 16MB -> 88MB total

  hipLaunchKernelGGL(cvt_x_kernel, dim3((M_ * D_) / (256 * 8)), dim3(256), 0, stream, x, xb);
  hipLaunchKernelGGL(transpose_w4_kernel, dim3(256, 4), dim3(256), 0, stream,
                     Wq, Wk, Wv, Wp, WqT, WkT, WvT, WpT);

  hipLaunchKernelGGL(gemm_qkv_kernel, dim3(D_ / BN, M_ / BM, 3), dim3(256), 0, stream,
                     xb, WqT, WkT, WvT, bq, bk, bv, Qb, Kb, Vb);

  hipLaunchKernelGGL(transpose_v_kernel, dim3(16, 32, 4), dim3(256), 0, stream, Vb, Vtg);

  hipLaunchKernelGGL(attn_kernel, dim3(8, B_ * NH_), dim3(256), 0, stream, Qb, Kb, Vtg, Ob);

  hipLaunchKernelGGL(gemm_proj_kernel, dim3(D_ / BN, M_ / BM), dim3(256), 0, stream,
                     Ob, WpT, bp, (float*)d_out);
}